// Round 3
// baseline (566.161 us; speedup 1.0000x reference)
//
#include <hip/hip_runtime.h>
#include <hip/hip_bf16.h>

// Problem constants (B=32, L=256 -> 8192 tokens)
#define N_TOK   8192
#define DMODEL  256
#define NFEAT   8
#define DFEAT   64
#define DIN     320     // DMODEL + DFEAT
#define DRTR    256
#define NE      8
#define DH      512
#define TB      8       // tokens per router block (1024 blocks -> 4/CU)
#define TE      16      // tokens per expert tile (LDS 33KB -> 4 blocks/CU)

// d_out layout (floats): [stage_delta 8192*256][gate_weights 8192*8][gate_logits 8192*8]
#define OUT_GATEW  (N_TOK*DMODEL)
#define OUT_LOGITS (N_TOK*DMODEL + N_TOK*NE)

__device__ __forceinline__ float gelu_tanh(float v){
  // jax.nn.gelu(approximate=True); tanh via exp(-2|u|) (no overflow)
  float u = 0.7978845608028654f * (v + 0.044715f * v * v * v);
  float a = fabsf(u);
  float e = __expf(-2.0f * a);
  float t = (1.0f - e) / (1.0f + e);
  t = copysignf(t, u);
  return 0.5f * v * (1.0f + t);
}

__global__ void k_init(int* __restrict__ cnts){
  if (threadIdx.x < NE) cnts[threadIdx.x] = 0;
}

// Router: 8 tokens/block, 256 threads, 1024 blocks (4 resident blocks/CU).
// LDS: x[8][320] + hr[8][260] + partials + logits ~ 20 KB.
__global__ __launch_bounds__(256, 4) void k_router(
    const float* __restrict__ hidden, const float* __restrict__ feat,
    const float* __restrict__ Wf, const float* __restrict__ bfe,
    const float* __restrict__ Wr1, const float* __restrict__ br1,
    const float* __restrict__ Wr2, const float* __restrict__ br2,
    float* __restrict__ out,
    int* __restrict__ cnts, unsigned* __restrict__ lists, float* __restrict__ topw)
{
  __shared__ float x_lds[TB*DIN];      // 2560 floats
  __shared__ float hr_lds[TB*260];     // 2080 floats (stride 260 keeps f4 alignment)
  __shared__ float part_lds[256];
  __shared__ float lg_lds[TB*NE];
  const int tid = threadIdx.x;
  const int t0 = blockIdx.x * TB;

  // zero this block's chunk of stage_delta (d_out re-poisoned each call)
  {
    float4 z = make_float4(0.f,0.f,0.f,0.f);
    float4* dst = ((float4*)out) + (size_t)blockIdx.x*512 + tid;
    dst[0] = z; dst[256] = z;
  }
  // stage hidden -> x[:, 0:256]
  {
    int lane = tid & 63, tq = tid >> 6;
    #pragma unroll
    for (int r=0;r<2;r++){
      int t = tq + r*4;
      float4 h4 = ((const float4*)(hidden + (size_t)(t0+t)*DMODEL))[lane];
      ((float4*)(x_lds + t*DIN))[lane] = h4;
    }
  }
  // feature embedding -> x[:, 256:320]
  #pragma unroll
  for (int rep=0;rep<2;rep++){
    int idx = rep*256 + tid;            // 8 tokens * 64 cols
    int t = idx >> 6, j = idx & 63;
    float acc = bfe[j];
    #pragma unroll
    for (int f=0; f<NFEAT; f++) acc += feat[(size_t)(t0+t)*NFEAT + f] * Wf[f*DFEAT + j];
    x_lds[t*DIN + DMODEL + j] = acc;
  }
  __syncthreads();

  // hr = gelu(x @ Wr1 + br1): thread = (j-pair jg, token-half th), 4 tokens each
  const int jg = tid & 127;
  const int th = tid >> 7;
  {
    float2 b = ((const float2*)br1)[jg];
    float2 acc[4];
    #pragma unroll
    for (int t=0;t<4;t++) acc[t] = b;
    const float2* W1 = ((const float2*)Wr1) + jg;   // row stride = 128 float2

    auto fma_chunk = [&](int i4, const float2 (&w)[4]){
      #pragma unroll
      for (int t=0;t<4;t++){
        float4 xv = ((const float4*)x_lds)[(th*4+t)*80 + i4];   // wave-broadcast b128
        acc[t].x += xv.x*w[0].x + xv.y*w[1].x + xv.z*w[2].x + xv.w*w[3].x;
        acc[t].y += xv.x*w[0].y + xv.y*w[1].y + xv.z*w[2].y + xv.w*w[3].y;
      }
    };
    float2 w[4];
    #pragma unroll
    for (int r=0;r<4;r++) w[r] = W1[r*128];
    for (int i4=0;i4<79;i4++){            // prefetch next 4 Wr1 rows under FMAs
      float2 wn[4];
      #pragma unroll
      for (int r=0;r<4;r++) wn[r] = W1[(i4*4+4+r)*128];
      fma_chunk(i4, w);
      #pragma unroll
      for (int r=0;r<4;r++) w[r] = wn[r];
    }
    fma_chunk(79, w);
    #pragma unroll
    for (int t=0;t<4;t++){
      hr_lds[(th*4+t)*260 + jg*2]     = gelu_tanh(acc[t].x);
      hr_lds[(th*4+t)*260 + jg*2 + 1] = gelu_tanh(acc[t].y);
    }
  }
  __syncthreads();
  // gate logits, 4-way split dot: thread = (q = tid>>6, t = (tid>>3)&7, e = tid&7)
  {
    int q = tid >> 6, rr = tid & 63, t = rr >> 3, e = rr & 7;
    float a0=0.f, a1=0.f, a2=0.f, a3=0.f;
    #pragma unroll 4
    for (int k4=0;k4<16;k4++){
      float4 h4 = ((const float4*)hr_lds)[t*65 + q*16 + k4];
      int row = q*64 + k4*4;
      a0 += h4.x * Wr2[(row+0)*NE + e];
      a1 += h4.y * Wr2[(row+1)*NE + e];
      a2 += h4.z * Wr2[(row+2)*NE + e];
      a3 += h4.w * Wr2[(row+3)*NE + e];
    }
    part_lds[tid] = (a0+a1)+(a2+a3);
  }
  __syncthreads();
  if (tid < TB*NE){
    int t = tid >> 3, e = tid & 7;
    float lg = br2[e] + part_lds[tid] + part_lds[tid+64] + part_lds[tid+128] + part_lds[tid+192];
    out[OUT_LOGITS + (size_t)(t0+t)*NE + e] = lg;   // TEMP == 1.0
    lg_lds[t*NE + e] = lg;
  }
  __syncthreads();
  // top-2 (lax.top_k tie-break: lowest index wins -> strict '>'), softmax over top-2
  if (tid < TB){
    int t = tid;
    float v1 = lg_lds[t*NE]; int i1 = 0;
    #pragma unroll
    for (int e=1;e<NE;e++){ float v = lg_lds[t*NE+e]; if (v > v1){ v1 = v; i1 = e; } }
    float v2 = -3.4e38f; int i2 = -1;
    #pragma unroll
    for (int e=0;e<NE;e++){
      if (e == i1) continue;
      float v = lg_lds[t*NE+e]; if (v > v2){ v2 = v; i2 = e; }
    }
    float d   = expf(v2 - v1);          // in (0,1], stable
    float inv = 1.0f/(1.0f + d);
    float w1 = inv, w2 = d*inv;
    #pragma unroll
    for (int e=0;e<NE;e++){
      float gv = (e==i1) ? w1 : ((e==i2) ? w2 : 0.f);
      out[OUT_GATEW + (size_t)(t0+t)*NE + e] = gv;
    }
    int p1 = atomicAdd(&cnts[i1], 1);
    lists[i1*N_TOK + p1] = (unsigned)(((t0+t)<<1));
    int p2 = atomicAdd(&cnts[i2], 1);
    lists[i2*N_TOK + p2] = (unsigned)(((t0+t)<<1) | 1);
    topw[(t0+t)*2]   = w1;
    topw[(t0+t)*2+1] = w2;
  }
}

// Expert: 16 token-slots/tile, 256 threads. LDS union 32 KB -> 4 blocks/CU.
// Grid = 512 tiles * 8 experts; block = tile*8 + e so expert e pins to XCD e
// (round-robin blockIdx%8 -> XCD): expert weights stay hot in ONE XCD's L2.
__global__ __launch_bounds__(256, 4) void k_expert(
    const float* __restrict__ hidden, const float* __restrict__ feat,
    const float* __restrict__ Wf, const float* __restrict__ bfe,
    const int* __restrict__ cnts, const unsigned* __restrict__ lists,
    const float* __restrict__ topw,
    const float* __restrict__ We1, const float* __restrict__ be1,
    const float* __restrict__ We2, const float* __restrict__ be2,
    float* __restrict__ out)
{
  __shared__ float smem[TE*DH];       // 32768 B (union: x[16][320] then he[16][512])
  __shared__ int   tok_lds[TE];
  __shared__ float w_lds[TE];

  const int e    = blockIdx.x & 7;
  const int tile = blockIdx.x >> 3;
  const int cnt  = cnts[e];
  const int start = tile * TE;
  if (start >= cnt) return;           // uniform early-exit before any barrier
  const int nt  = min(TE, cnt - start);
  const int tid = threadIdx.x;

  if (tid < TE){
    if (tid < nt){
      unsigned ent = lists[e*N_TOK + start + tid];
      int tok = (int)(ent >> 1);
      tok_lds[tid] = tok;
      w_lds[tid]   = topw[tok*2 + (ent & 1)];
    } else { tok_lds[tid] = -1; w_lds[tid] = 0.f; }
  }
  __syncthreads();
  // gather x = concat(hidden[tok], feat_emb[tok]) into LDS
  {
    int lane = tid & 63, tq = tid >> 6;
    #pragma unroll
    for (int r=0;r<4;r++){
      int t = tq + r*4;
      int tok = tok_lds[t];
      float4 h4 = make_float4(0.f,0.f,0.f,0.f);
      if (tok >= 0) h4 = ((const float4*)(hidden + (size_t)tok*DMODEL))[lane];
      ((float4*)(smem + t*DIN))[lane] = h4;
    }
  }
  #pragma unroll
  for (int rep=0;rep<4;rep++){
    int idx = rep*256 + tid;
    int t = idx >> 6, j = idx & 63;
    int tok = tok_lds[t];
    float acc = 0.f;
    if (tok >= 0){
      acc = bfe[j];
      #pragma unroll
      for (int f=0; f<NFEAT; f++) acc += feat[(size_t)tok*NFEAT + f] * Wf[f*DFEAT + j];
    }
    smem[t*DIN + DMODEL + j] = acc;
  }
  __syncthreads();

  const int hg = tid & 127;   // phase1: h = hg*4+{0..3}; phase2: o = hg*2+{0,1}
  const int th = tid >> 7;    // token half: tokens th*8 .. th*8+7
  // phase 1: he = gelu(x @ We1[e] + be1[e]) -- accumulate in regs
  float2 acc1[8][2];
  {
    const float4* W1 = ((const float4*)(We1 + (size_t)e*DIN*DH)) + hg;  // row = 128 float4
    float4 b1 = ((const float4*)(be1 + (size_t)e*DH))[hg];
    #pragma unroll
    for (int t=0;t<8;t++){ acc1[t][0] = make_float2(b1.x,b1.y); acc1[t][1] = make_float2(b1.z,b1.w); }

    auto fma_chunk1 = [&](int i4, const float4 (&w)[4]){
      #pragma unroll
      for (int t=0;t<8;t++){
        float4 xv = ((const float4*)smem)[(th*8+t)*80 + i4];   // wave-broadcast b128
        acc1[t][0].x += xv.x*w[0].x + xv.y*w[1].x + xv.z*w[2].x + xv.w*w[3].x;
        acc1[t][0].y += xv.x*w[0].y + xv.y*w[1].y + xv.z*w[2].y + xv.w*w[3].y;
        acc1[t][1].x += xv.x*w[0].z + xv.y*w[1].z + xv.z*w[2].z + xv.w*w[3].z;
        acc1[t][1].y += xv.x*w[0].w + xv.y*w[1].w + xv.z*w[2].w + xv.w*w[3].w;
      }
    };
    float4 w[4];
    #pragma unroll
    for (int r=0;r<4;r++) w[r] = W1[r*128];
    for (int i4=0;i4<79;i4++){            // prefetch next 4 We1 rows under 128 FMAs
      float4 wn[4];
      #pragma unroll
      for (int r=0;r<4;r++) wn[r] = W1[(i4*4+4+r)*128];
      fma_chunk1(i4, w);
      #pragma unroll
      for (int r=0;r<4;r++) w[r] = wn[r];
    }
    fma_chunk1(79, w);
  }
  __syncthreads();    // x region dead; reuse as he
  #pragma unroll
  for (int t=0;t<8;t++){
    float4 o4 = make_float4(gelu_tanh(acc1[t][0].x), gelu_tanh(acc1[t][0].y),
                            gelu_tanh(acc1[t][1].x), gelu_tanh(acc1[t][1].y));
    ((float4*)(smem + (size_t)(th*8+t)*DH))[hg] = o4;   // conflict-free b128
  }
  __syncthreads();
  // phase 2: eo = he @ We2[e] + be2[e]; 8-row chunks (prefetch hides L2 latency)
  {
    const float2* W2 = ((const float2*)(We2 + (size_t)e*DH*DMODEL)) + hg; // row = 128 float2
    float2 acc2[8];
    #pragma unroll
    for (int t=0;t<8;t++) acc2[t] = make_float2(0.f,0.f);

    auto fma_chunk2 = [&](int h8, const float2 (&u)[8]){
      #pragma unroll
      for (int t=0;t<8;t++){
        int base = (th*8+t)*128 + h8*2;
        float4 hv0 = ((const float4*)smem)[base];      // wave-broadcast b128
        float4 hv1 = ((const float4*)smem)[base+1];
        acc2[t].x += hv0.x*u[0].x + hv0.y*u[1].x + hv0.z*u[2].x + hv0.w*u[3].x
                   + hv1.x*u[4].x + hv1.y*u[5].x + hv1.z*u[6].x + hv1.w*u[7].x;
        acc2[t].y += hv0.x*u[0].y + hv0.y*u[1].y + hv0.z*u[2].y + hv0.w*u[3].y
                   + hv1.x*u[4].y + hv1.y*u[5].y + hv1.z*u[6].y + hv1.w*u[7].y;
      }
    };
    float2 u[8];
    #pragma unroll
    for (int r=0;r<8;r++) u[r] = W2[r*128];
    for (int h8=0;h8<63;h8++){
      float2 un[8];
      #pragma unroll
      for (int r=0;r<8;r++) un[r] = W2[(h8*8+8+r)*128];
      fma_chunk2(h8, u);
      #pragma unroll
      for (int r=0;r<8;r++) u[r] = un[r];
    }
    fma_chunk2(63, u);

    float2 b2 = ((const float2*)(be2 + (size_t)e*DMODEL))[hg];
    #pragma unroll
    for (int t=0;t<8;t++){
      int tt = th*8 + t;
      if (tt < nt){
        int tok  = tok_lds[tt];
        float w  = w_lds[tt];
        atomicAdd(out + (size_t)tok*DMODEL + hg*2,     w*(acc2[t].x + b2.x));
        atomicAdd(out + (size_t)tok*DMODEL + hg*2 + 1, w*(acc2[t].y + b2.y));
      }
    }
  }
}

extern "C" void kernel_launch(void* const* d_in, const int* in_sizes, int n_in,
                              void* d_out, int out_size, void* d_ws, size_t ws_size,
                              hipStream_t stream)
{
  (void)in_sizes; (void)n_in; (void)out_size; (void)ws_size;
  const float* hidden = (const float*)d_in[0];
  const float* feat   = (const float*)d_in[1];
  const float* Wf     = (const float*)d_in[2];
  const float* bfe    = (const float*)d_in[3];
  const float* Wr1    = (const float*)d_in[4];
  const float* br1    = (const float*)d_in[5];
  const float* Wr2    = (const float*)d_in[6];
  const float* br2    = (const float*)d_in[7];
  const float* We1    = (const float*)d_in[8];
  const float* be1    = (const float*)d_in[9];
  const float* We2    = (const float*)d_in[10];
  const float* be2    = (const float*)d_in[11];
  float* out = (float*)d_out;

  // workspace: [cnts 8*int][pad][lists 8*8192*u32][topw 16384*f32]
  char* ws = (char*)d_ws;
  int*      cnts  = (int*)ws;
  unsigned* lists = (unsigned*)(ws + 256);
  float*    topw  = (float*)(ws + 256 + NE*N_TOK*4);

  hipLaunchKernelGGL(k_init, dim3(1), dim3(64), 0, stream, cnts);
  hipLaunchKernelGGL(k_router, dim3(N_TOK/TB), dim3(256), 0, stream,
                     hidden, feat, Wf, bfe, Wr1, br1, Wr2, br2,
                     out, cnts, lists, topw);
  hipLaunchKernelGGL(k_expert, dim3((N_TOK/TE)*NE), dim3(256), 0, stream,
                     hidden, feat, Wf, bfe, cnts, lists, topw,
                     We1, be1, We2, be2, out);
}

// Round 4
// 376.536 us; speedup vs baseline: 1.5036x; 1.5036x over previous
//
#include <hip/hip_runtime.h>
#include <hip/hip_bf16.h>

// Problem: B=32, L=256 -> 8192 tokens; DIN=320, DR=256, DH=512, E=8, top-2.
#define N_TOK   8192
#define DMODEL  256
#define NFEAT   8
#define DFEAT   64
#define DIN     320
#define DRTR    256
#define NE      8
#define DH      512
#define TB      8       // tokens per router block (1024 blocks -> 4/CU)
#define TE      32      // tokens per expert tile

// d_out layout (floats): [stage_delta 8192*256][gate_weights 8192*8][gate_logits 8192*8]
#define OUT_GATEW  (N_TOK*DMODEL)
#define OUT_LOGITS (N_TOK*DMODEL + N_TOK*NE)

typedef short v8s __attribute__((ext_vector_type(8)));   // 8 bf16 (4 VGPR) MFMA A/B frag
typedef float v4f __attribute__((ext_vector_type(4)));   // 4 f32 MFMA C/D frag

__device__ __forceinline__ unsigned short f2bf(float f){   // RNE f32->bf16
  unsigned u = __float_as_uint(f);
  return (unsigned short)((u + 0x7FFFu + ((u>>16)&1u)) >> 16);
}
__device__ __forceinline__ float bf2f(unsigned short h){
  return __uint_as_float(((unsigned)h)<<16);
}

__device__ __forceinline__ float gelu_tanh(float v){
  float u = 0.7978845608028654f * (v + 0.044715f * v * v * v);
  float a = fabsf(u);
  float e = __expf(-2.0f * a);
  float t = (1.0f - e) / (1.0f + e);
  t = copysignf(t, u);
  return 0.5f * v * (1.0f + t);
}

__global__ void k_init(int* __restrict__ cnts){
  if (threadIdx.x < NE) cnts[threadIdx.x] = 0;
}

// ---- weight prep: split-bf16 (hi+lo) planes in MFMA B-fragment order ----
// frag layout: plane[ ((e*KSTEPS + kstep)*NTILES + nt)*64 + lane ]*8 + e8
//   maps to W[k = kstep*32 + (lane>>4)*8 + e8][n = nt*16 + (lane&15)]
// A-side uses the SAME k-mapping (k-contiguous per lane) -> any consistent
// bijection is correct since CDNA A/B lane layouts are symmetric in K.
__global__ __launch_bounds__(256) void k_prep1(const float* __restrict__ W,
                                               unsigned short* __restrict__ dh,
                                               unsigned short* __restrict__ dl){
  int gid = blockIdx.x*256 + threadIdx.x;        // 8*10*32*64 lanes
  int l = gid & 63; int w = gid >> 6;
  int nt = w & 31; w >>= 5; int kstep = w % 10; int e = w / 10;
  int n = nt*16 + (l&15);
  int kb = kstep*32 + ((l>>4)<<3);
  const float* src = W + ((size_t)e*DIN + kb)*DH + n;
  unsigned short hs[8], ls[8];
  #pragma unroll
  for (int i=0;i<8;i++){
    float v = src[(size_t)i*DH];
    unsigned short h = f2bf(v);
    hs[i] = h; ls[i] = f2bf(v - bf2f(h));
  }
  size_t off = (size_t)gid*8;
  *(v8s*)(dh+off) = *(v8s*)hs;
  *(v8s*)(dl+off) = *(v8s*)ls;
}

__global__ __launch_bounds__(256) void k_prep2(const float* __restrict__ W,
                                               unsigned short* __restrict__ dh,
                                               unsigned short* __restrict__ dl){
  int gid = blockIdx.x*256 + threadIdx.x;        // 8*16*16*64 lanes
  int l = gid & 63; int w = gid >> 6;
  int nt = w & 15; w >>= 4; int kstep = w & 15; int e = w >> 4;
  int n = nt*16 + (l&15);
  int kb = kstep*32 + ((l>>4)<<3);
  const float* src = W + ((size_t)e*DH + kb)*DMODEL + n;
  unsigned short hs[8], ls[8];
  #pragma unroll
  for (int i=0;i<8;i++){
    float v = src[(size_t)i*DMODEL];
    unsigned short h = f2bf(v);
    hs[i] = h; ls[i] = f2bf(v - bf2f(h));
  }
  size_t off = (size_t)gid*8;
  *(v8s*)(dh+off) = *(v8s*)hs;
  *(v8s*)(dl+off) = *(v8s*)ls;
}

// ---- router: fp32 exact (top-k selection must not move), latency-optimized ----
__global__ __launch_bounds__(256) void k_router(
    const float* __restrict__ hidden, const float* __restrict__ feat,
    const float* __restrict__ Wf, const float* __restrict__ bfe,
    const float* __restrict__ Wr1, const float* __restrict__ br1,
    const float* __restrict__ Wr2, const float* __restrict__ br2,
    float* __restrict__ out,
    int* __restrict__ cnts, unsigned* __restrict__ lists, float* __restrict__ topw)
{
  __shared__ float x_lds[TB*DIN];      // 10240 B
  __shared__ float hr_lds[TB*260];     // 8320 B
  __shared__ float part_lds[256];
  __shared__ float lg_lds[TB*NE];
  const int tid = threadIdx.x;
  const int t0 = blockIdx.x * TB;

  // zero this block's stage_delta slab (8*256 floats)
  {
    float4 z = make_float4(0.f,0.f,0.f,0.f);
    float4* dst = ((float4*)out) + (size_t)blockIdx.x*512 + tid;
    dst[0] = z; dst[256] = z;
  }
  // stage hidden -> x[:, 0:256]
  #pragma unroll
  for (int r=0;r<2;r++){
    int idx = r*256 + tid; int t = idx >> 6, lane = idx & 63;
    ((float4*)(x_lds + t*DIN))[lane] =
        ((const float4*)(hidden + (size_t)(t0+t)*DMODEL))[lane];
  }
  // feature embedding -> x[:, 256:320]
  #pragma unroll
  for (int r=0;r<2;r++){
    int idx = r*256 + tid; int t = idx >> 6, j = idx & 63;
    float acc = bfe[j];
    #pragma unroll
    for (int f=0; f<NFEAT; f++) acc += feat[(size_t)(t0+t)*NFEAT + f] * Wf[f*DFEAT + j];
    x_lds[t*DIN + DMODEL + j] = acc;
  }
  __syncthreads();

  // hr = gelu(x @ Wr1 + br1): thread = (jq = tid&63 -> cols jq*4..+3, tg = tid>>6 -> 2 tokens)
  const int jq = tid & 63;
  const int tg = tid >> 6;
  {
    float4 b4 = ((const float4*)br1)[jq];
    float4 acc0 = b4, acc1 = b4;
    const float4* W1 = ((const float4*)Wr1) + jq;   // row stride 64 float4

    auto fma4 = [&](int i4, const float4 (&w)[4]){
      float4 xa = *(const float4*)&x_lds[(tg*2+0)*DIN + i4*4];
      float4 xb = *(const float4*)&x_lds[(tg*2+1)*DIN + i4*4];
      acc0.x += xa.x*w[0].x + xa.y*w[1].x + xa.z*w[2].x + xa.w*w[3].x;
      acc0.y += xa.x*w[0].y + xa.y*w[1].y + xa.z*w[2].y + xa.w*w[3].y;
      acc0.z += xa.x*w[0].z + xa.y*w[1].z + xa.z*w[2].z + xa.w*w[3].z;
      acc0.w += xa.x*w[0].w + xa.y*w[1].w + xa.z*w[2].w + xa.w*w[3].w;
      acc1.x += xb.x*w[0].x + xb.y*w[1].x + xb.z*w[2].x + xb.w*w[3].x;
      acc1.y += xb.x*w[0].y + xb.y*w[1].y + xb.z*w[2].y + xb.w*w[3].y;
      acc1.z += xb.x*w[0].z + xb.y*w[1].z + xb.z*w[2].z + xb.w*w[3].z;
      acc1.w += xb.x*w[0].w + xb.y*w[1].w + xb.z*w[2].w + xb.w*w[3].w;
    };
    float4 wA[4], wB[4];
    #pragma unroll
    for (int r=0;r<4;r++) wA[r] = W1[(0*4+r)*64];
    for (int i4=0;i4<80;i4+=2){                 // unroll-by-2 double-buffer
      #pragma unroll
      for (int r=0;r<4;r++) wB[r] = (i4+1<80) ? W1[((i4+1)*4+r)*64] : wA[r];
      fma4(i4, wA);
      if (i4+2<80){
        #pragma unroll
        for (int r=0;r<4;r++) wA[r] = W1[((i4+2)*4+r)*64];
      }
      if (i4+1<80) fma4(i4+1, wB);
    }
    *(float4*)&hr_lds[(tg*2+0)*260 + jq*4] =
        make_float4(gelu_tanh(acc0.x),gelu_tanh(acc0.y),gelu_tanh(acc0.z),gelu_tanh(acc0.w));
    *(float4*)&hr_lds[(tg*2+1)*260 + jq*4] =
        make_float4(gelu_tanh(acc1.x),gelu_tanh(acc1.y),gelu_tanh(acc1.z),gelu_tanh(acc1.w));
  }
  __syncthreads();
  // gate logits, 4-way split dot (identical summation structure to passing R3)
  {
    int q = tid >> 6, rr = tid & 63, t = rr >> 3, e = rr & 7;
    float a0=0.f, a1=0.f, a2=0.f, a3=0.f;
    #pragma unroll 4
    for (int k4=0;k4<16;k4++){
      float4 h4 = ((const float4*)hr_lds)[t*65 + q*16 + k4];
      int row = q*64 + k4*4;
      a0 += h4.x * Wr2[(row+0)*NE + e];
      a1 += h4.y * Wr2[(row+1)*NE + e];
      a2 += h4.z * Wr2[(row+2)*NE + e];
      a3 += h4.w * Wr2[(row+3)*NE + e];
    }
    part_lds[tid] = (a0+a1)+(a2+a3);
  }
  __syncthreads();
  if (tid < TB*NE){
    int t = tid >> 3, e = tid & 7;
    float lg = br2[e] + part_lds[tid] + part_lds[tid+64] + part_lds[tid+128] + part_lds[tid+192];
    out[OUT_LOGITS + (size_t)(t0+t)*NE + e] = lg;   // TEMP == 1.0
    lg_lds[t*NE + e] = lg;
  }
  __syncthreads();
  if (tid < TB){
    int t = tid;
    float v1 = lg_lds[t*NE]; int i1 = 0;
    #pragma unroll
    for (int e=1;e<NE;e++){ float v = lg_lds[t*NE+e]; if (v > v1){ v1 = v; i1 = e; } }
    float v2 = -3.4e38f; int i2 = -1;
    #pragma unroll
    for (int e=0;e<NE;e++){
      if (e == i1) continue;
      float v = lg_lds[t*NE+e]; if (v > v2){ v2 = v; i2 = e; }
    }
    float d   = expf(v2 - v1);
    float inv = 1.0f/(1.0f + d);
    float w1 = inv, w2 = d*inv;
    #pragma unroll
    for (int e=0;e<NE;e++){
      float gv = (e==i1) ? w1 : ((e==i2) ? w2 : 0.f);
      out[OUT_GATEW + (size_t)(t0+t)*NE + e] = gv;
    }
    int p1 = atomicAdd(&cnts[i1], 1);
    lists[i1*N_TOK + p1] = (unsigned)(((t0+t)<<1));
    int p2 = atomicAdd(&cnts[i2], 1);
    lists[i2*N_TOK + p2] = (unsigned)(((t0+t)<<1) | 1);
    topw[(t0+t)*2]   = w1;
    topw[(t0+t)*2+1] = w2;
  }
}

// ---- expert: split-bf16 MFMA (3 products: xh*wh + xl*wh + xh*wl) ----
// 32 tokens/tile, 4 waves. LDS union (ushorts):
//   phase A: xh[32][328] @0, xl @10496   (pad 328 -> 2-way-free bank spread)
//   phase B: heh[32][520] @0, hel @16640 (pad 520)
// 66.8 KB -> 2 blocks/CU. expert e = blockIdx&7 pins to XCD e (weights L2-hot).
#define XLOFF 10496
#define HELOFF 16640
__global__ __launch_bounds__(256) void k_expert(
    const float* __restrict__ hidden, const float* __restrict__ feat,
    const float* __restrict__ Wf, const float* __restrict__ bfe,
    const int* __restrict__ cnts, const unsigned* __restrict__ lists,
    const float* __restrict__ topw,
    const unsigned short* __restrict__ W1h, const unsigned short* __restrict__ W1l,
    const unsigned short* __restrict__ W2h, const unsigned short* __restrict__ W2l,
    const float* __restrict__ be1, const float* __restrict__ be2,
    float* __restrict__ out)
{
  __shared__ unsigned short sm[33280];   // 66560 B union
  __shared__ int   tok_lds[TE];
  __shared__ float w_lds[TE];

  const int e    = blockIdx.x & 7;
  const int tile = blockIdx.x >> 3;
  const int cnt  = cnts[e];
  const int start = tile * TE;
  if (start >= cnt) return;
  const int ntk = min(TE, cnt - start);
  const int tid = threadIdx.x;

  if (tid < TE){
    if (tid < ntk){
      unsigned ent = lists[e*N_TOK + start + tid];
      int tok = (int)(ent >> 1);
      tok_lds[tid] = tok;
      w_lds[tid]   = topw[tok*2 + (ent & 1)];
    } else { tok_lds[tid] = -1; w_lds[tid] = 0.f; }
  }
  __syncthreads();
  // stage x split-bf16: hidden part (32 rows x 64 float4)
  {
    int lane = tid & 63, tq = tid >> 6;
    #pragma unroll
    for (int r=0;r<8;r++){
      int t = r*4 + tq;
      int tok = tok_lds[t];
      float4 h4 = make_float4(0.f,0.f,0.f,0.f);
      if (tok >= 0) h4 = ((const float4*)(hidden + (size_t)tok*DMODEL))[lane];
      unsigned short h0=f2bf(h4.x),h1=f2bf(h4.y),h2=f2bf(h4.z),h3=f2bf(h4.w);
      unsigned short l0=f2bf(h4.x-bf2f(h0)),l1=f2bf(h4.y-bf2f(h1)),
                     l2=f2bf(h4.z-bf2f(h2)),l3=f2bf(h4.w-bf2f(h3));
      uint2 hp, lp;
      hp.x = (unsigned)h0 | ((unsigned)h1<<16); hp.y = (unsigned)h2 | ((unsigned)h3<<16);
      lp.x = (unsigned)l0 | ((unsigned)l1<<16); lp.y = (unsigned)l2 | ((unsigned)l3<<16);
      *(uint2*)&sm[t*328 + lane*4]         = hp;
      *(uint2*)&sm[XLOFF + t*328 + lane*4] = lp;
    }
  }
  // feature embedding part (32 rows x 64 cols)
  #pragma unroll
  for (int r=0;r<8;r++){
    int idx = r*256 + tid; int t = idx >> 6, j = idx & 63;
    int tok = tok_lds[t];
    float acc = 0.f;
    if (tok >= 0){
      acc = bfe[j];
      #pragma unroll
      for (int f=0; f<NFEAT; f++) acc += feat[(size_t)tok*NFEAT + f] * Wf[f*DFEAT + j];
    }
    unsigned short h = f2bf(acc);
    sm[t*328 + DMODEL + j]         = h;
    sm[XLOFF + t*328 + DMODEL + j] = f2bf(acc - bf2f(h));
  }
  __syncthreads();

  const int wv = tid >> 6;      // wave 0..3
  const int l  = tid & 63;
  const int lg = l >> 4;        // k-group
  const int lr = l & 15;        // A-row / B-col within tile

  // phase 1: he = gelu(x @ We1[e] + be1[e]); wave owns 8 n-tiles (128 cols)
  v4f acc1[2][8];
  {
    v4f z = {0.f,0.f,0.f,0.f};
    #pragma unroll
    for (int m=0;m<2;m++)
      #pragma unroll
      for (int j=0;j<8;j++) acc1[m][j] = z;
    const unsigned short* p1h = W1h + (size_t)e*163840;
    const unsigned short* p1l = W1l + (size_t)e*163840;
    for (int ks=0; ks<10; ++ks){
      v8s ah0 = *(const v8s*)&sm[( 0+lr)*328 + ks*32 + lg*8];
      v8s ah1 = *(const v8s*)&sm[(16+lr)*328 + ks*32 + lg*8];
      v8s al0 = *(const v8s*)&sm[XLOFF + ( 0+lr)*328 + ks*32 + lg*8];
      v8s al1 = *(const v8s*)&sm[XLOFF + (16+lr)*328 + ks*32 + lg*8];
      #pragma unroll
      for (int j=0;j<8;++j){
        int nt = wv*8 + j;
        size_t boff = ((size_t)(ks*32 + nt)*64 + l)*8;
        v8s bh = *(const v8s*)(p1h + boff);
        v8s bl = *(const v8s*)(p1l + boff);
        acc1[0][j] = __builtin_amdgcn_mfma_f32_16x16x32_bf16(ah0, bh, acc1[0][j], 0,0,0);
        acc1[1][j] = __builtin_amdgcn_mfma_f32_16x16x32_bf16(ah1, bh, acc1[1][j], 0,0,0);
        acc1[0][j] = __builtin_amdgcn_mfma_f32_16x16x32_bf16(al0, bh, acc1[0][j], 0,0,0);
        acc1[1][j] = __builtin_amdgcn_mfma_f32_16x16x32_bf16(al1, bh, acc1[1][j], 0,0,0);
        acc1[0][j] = __builtin_amdgcn_mfma_f32_16x16x32_bf16(ah0, bl, acc1[0][j], 0,0,0);
        acc1[1][j] = __builtin_amdgcn_mfma_f32_16x16x32_bf16(ah1, bl, acc1[1][j], 0,0,0);
      }
    }
  }
  __syncthreads();   // x region dead -> reuse as he planes
  // epilogue 1: bias + gelu + split-bf16 -> he LDS (C/D layout m89: row=(l>>4)*4+r, col=l&15)
  {
    #pragma unroll
    for (int j=0;j<8;++j){
      int col = (wv*8+j)*16 + lr;
      float b1 = be1[e*DH + col];
      #pragma unroll
      for (int m=0;m<2;m++)
        #pragma unroll
        for (int r=0;r<4;r++){
          float v = gelu_tanh(acc1[m][j][r] + b1);
          int row = m*16 + lg*4 + r;
          unsigned short h = f2bf(v);
          sm[row*520 + col]          = h;
          sm[HELOFF + row*520 + col] = f2bf(v - bf2f(h));
        }
    }
  }
  __syncthreads();
  // phase 2: eo = he @ We2[e] + be2[e]; wave owns 4 n-tiles (64 cols)
  v4f acc2[2][4];
  {
    v4f z = {0.f,0.f,0.f,0.f};
    #pragma unroll
    for (int m=0;m<2;m++)
      #pragma unroll
      for (int j=0;j<4;j++) acc2[m][j] = z;
    const unsigned short* p2h = W2h + (size_t)e*131072;
    const unsigned short* p2l = W2l + (size_t)e*131072;
    for (int ks=0; ks<16; ++ks){
      v8s ah0 = *(const v8s*)&sm[( 0+lr)*520 + ks*32 + lg*8];
      v8s ah1 = *(const v8s*)&sm[(16+lr)*520 + ks*32 + lg*8];
      v8s al0 = *(const v8s*)&sm[HELOFF + ( 0+lr)*520 + ks*32 + lg*8];
      v8s al1 = *(const v8s*)&sm[HELOFF + (16+lr)*520 + ks*32 + lg*8];
      #pragma unroll
      for (int j=0;j<4;++j){
        int nt = wv*4 + j;
        size_t boff = ((size_t)(ks*16 + nt)*64 + l)*8;
        v8s bh = *(const v8s*)(p2h + boff);
        v8s bl = *(const v8s*)(p2l + boff);
        acc2[0][j] = __builtin_amdgcn_mfma_f32_16x16x32_bf16(ah0, bh, acc2[0][j], 0,0,0);
        acc2[1][j] = __builtin_amdgcn_mfma_f32_16x16x32_bf16(ah1, bh, acc2[1][j], 0,0,0);
        acc2[0][j] = __builtin_amdgcn_mfma_f32_16x16x32_bf16(al0, bh, acc2[0][j], 0,0,0);
        acc2[1][j] = __builtin_amdgcn_mfma_f32_16x16x32_bf16(al1, bh, acc2[1][j], 0,0,0);
        acc2[0][j] = __builtin_amdgcn_mfma_f32_16x16x32_bf16(ah0, bl, acc2[0][j], 0,0,0);
        acc2[1][j] = __builtin_amdgcn_mfma_f32_16x16x32_bf16(ah1, bl, acc2[1][j], 0,0,0);
      }
    }
  }
  // epilogue 2: + be2, * gate, atomicAdd into stage_delta
  {
    #pragma unroll
    for (int j=0;j<4;++j){
      int col = (wv*4+j)*16 + lr;
      float b2 = be2[e*DMODEL + col];
      #pragma unroll
      for (int m=0;m<2;m++)
        #pragma unroll
        for (int r=0;r<4;r++){
          int row = m*16 + lg*4 + r;
          if (row < ntk){
            float w = w_lds[row];
            atomicAdd(out + (size_t)tok_lds[row]*DMODEL + col,
                      w*(acc2[m][j][r] + b2));
          }
        }
    }
  }
}

extern "C" void kernel_launch(void* const* d_in, const int* in_sizes, int n_in,
                              void* d_out, int out_size, void* d_ws, size_t ws_size,
                              hipStream_t stream)
{
  (void)in_sizes; (void)n_in; (void)out_size; (void)ws_size;
  const float* hidden = (const float*)d_in[0];
  const float* feat   = (const float*)d_in[1];
  const float* Wf     = (const float*)d_in[2];
  const float* bfe    = (const float*)d_in[3];
  const float* Wr1    = (const float*)d_in[4];
  const float* br1    = (const float*)d_in[5];
  const float* Wr2    = (const float*)d_in[6];
  const float* br2    = (const float*)d_in[7];
  const float* We1    = (const float*)d_in[8];
  const float* be1    = (const float*)d_in[9];
  const float* We2    = (const float*)d_in[10];
  const float* be2    = (const float*)d_in[11];
  float* out = (float*)d_out;

  // ws layout (bytes):
  //   0       cnts (8 int, pad 256)
  //   256     lists  8*8192*4   = 262144
  //   262400  topw   16384*4    =  65536
  //   327936  W1h    2,621,440
  //   2949376 W1l    2,621,440
  //   5570816 W2h    2,097,152
  //   7667968 W2l    2,097,152   -> total ~9.77 MB
  char* ws = (char*)d_ws;
  int*      cnts  = (int*)ws;
  unsigned* lists = (unsigned*)(ws + 256);
  float*    topw  = (float*)(ws + 262400);
  unsigned short* W1h = (unsigned short*)(ws + 327936);
  unsigned short* W1l = (unsigned short*)(ws + 2949376);
  unsigned short* W2h = (unsigned short*)(ws + 5570816);
  unsigned short* W2l = (unsigned short*)(ws + 7667968);

  hipLaunchKernelGGL(k_init, dim3(1), dim3(64), 0, stream, cnts);
  hipLaunchKernelGGL(k_prep1, dim3(640), dim3(256), 0, stream, We1, W1h, W1l);
  hipLaunchKernelGGL(k_prep2, dim3(512), dim3(256), 0, stream, We2, W2h, W2l);
  hipLaunchKernelGGL(k_router, dim3(N_TOK/TB), dim3(256), 0, stream,
                     hidden, feat, Wf, bfe, Wr1, br1, Wr2, br2,
                     out, cnts, lists, topw);
  hipLaunchKernelGGL(k_expert, dim3((N_TOK/TE)*NE), dim3(256), 0, stream,
                     hidden, feat, Wf, bfe, cnts, lists, topw,
                     W1h, W1l, W2h, W2l, be1, be2, out);
}

// Round 6
// 313.370 us; speedup vs baseline: 1.8067x; 1.2016x over previous
//
#include <hip/hip_runtime.h>
#include <hip/hip_bf16.h>

// Problem: B=32, L=256 -> 8192 tokens; DIN=320, DR=256, DH=512, E=8, top-2.
#define N_TOK   8192
#define DMODEL  256
#define NFEAT   8
#define DFEAT   64
#define DIN     320
#define DRTR    256
#define NE      8
#define DH      512
#define TB      8       // tokens per router block
#define TE      32      // tokens per expert tile

// d_out layout (floats): [stage_delta 8192*256][gate_weights 8192*8][gate_logits 8192*8]
#define OUT_GATEW  (N_TOK*DMODEL)
#define OUT_LOGITS (N_TOK*DMODEL + N_TOK*NE)

typedef short v8s __attribute__((ext_vector_type(8)));   // 8 bf16 (4 VGPR) MFMA A/B frag
typedef float v4f __attribute__((ext_vector_type(4)));   // 4 f32 MFMA C/D frag

__device__ __forceinline__ unsigned short f2bf(float f){   // RNE f32->bf16
  unsigned u = __float_as_uint(f);
  return (unsigned short)((u + 0x7FFFu + ((u>>16)&1u)) >> 16);
}
__device__ __forceinline__ float bf2f(unsigned short h){
  return __uint_as_float(((unsigned)h)<<16);
}

__device__ __forceinline__ float gelu_tanh(float v){
  float u = 0.7978845608028654f * (v + 0.044715f * v * v * v);
  float a = fabsf(u);
  float e = __expf(-2.0f * a);
  float t = (1.0f - e) / (1.0f + e);
  t = copysignf(t, u);
  return 0.5f * v * (1.0f + t);
}

__global__ void k_init(int* __restrict__ cnts){
  if (threadIdx.x < NE) cnts[threadIdx.x] = 0;
}

// ---- weight prep: split-bf16 (hi+lo) planes in MFMA B-fragment order ----
// plane[((e*KSTEPS + kstep)*NTILES + nt)*64 + lane]*8 + e8
//   -> W[k = kstep*32 + (lane>>4)*8 + e8][n = nt*16 + (lane&15)]
__global__ __launch_bounds__(256) void k_prep1(const float* __restrict__ W,
                                               unsigned short* __restrict__ dh,
                                               unsigned short* __restrict__ dl){
  int gid = blockIdx.x*256 + threadIdx.x;        // 8*10*32*64 lanes
  int l = gid & 63; int w = gid >> 6;
  int nt = w & 31; w >>= 5; int kstep = w % 10; int e = w / 10;
  int n = nt*16 + (l&15);
  int kb = kstep*32 + ((l>>4)<<3);
  const float* src = W + ((size_t)e*DIN + kb)*DH + n;
  unsigned short hs[8], ls[8];
  #pragma unroll
  for (int i=0;i<8;i++){
    float v = src[(size_t)i*DH];
    unsigned short h = f2bf(v);
    hs[i] = h; ls[i] = f2bf(v - bf2f(h));
  }
  size_t off = (size_t)gid*8;
  *(v8s*)(dh+off) = *(v8s*)hs;
  *(v8s*)(dl+off) = *(v8s*)ls;
}

__global__ __launch_bounds__(256) void k_prep2(const float* __restrict__ W,
                                               unsigned short* __restrict__ dh,
                                               unsigned short* __restrict__ dl){
  int gid = blockIdx.x*256 + threadIdx.x;        // 8*16*16*64 lanes
  int l = gid & 63; int w = gid >> 6;
  int nt = w & 15; w >>= 4; int kstep = w & 15; int e = w >> 4;
  int n = nt*16 + (l&15);
  int kb = kstep*32 + ((l>>4)<<3);
  const float* src = W + ((size_t)e*DH + kb)*DMODEL + n;
  unsigned short hs[8], ls[8];
  #pragma unroll
  for (int i=0;i<8;i++){
    float v = src[(size_t)i*DMODEL];
    unsigned short h = f2bf(v);
    hs[i] = h; ls[i] = f2bf(v - bf2f(h));
  }
  size_t off = (size_t)gid*8;
  *(v8s*)(dh+off) = *(v8s*)hs;
  *(v8s*)(dl+off) = *(v8s*)ls;
}

// ---- router: fp32 exact (top-k must not move). 4-deep weight prefetch. ----
__global__ __launch_bounds__(256) void k_router(
    const float* __restrict__ hidden, const float* __restrict__ feat,
    const float* __restrict__ Wf, const float* __restrict__ bfe,
    const float* __restrict__ Wr1, const float* __restrict__ br1,
    const float* __restrict__ Wr2, const float* __restrict__ br2,
    float* __restrict__ out,
    int* __restrict__ cnts, unsigned* __restrict__ lists, float* __restrict__ topw)
{
  __shared__ float x_lds[TB*DIN];
  __shared__ float hr_lds[TB*260];
  __shared__ float part_lds[256];
  __shared__ float lg_lds[TB*NE];
  const int tid = threadIdx.x;
  const int t0 = blockIdx.x * TB;

  // zero this block's stage_delta slab (8*256 floats)
  {
    float4 z = make_float4(0.f,0.f,0.f,0.f);
    float4* dst = ((float4*)out) + (size_t)blockIdx.x*512 + tid;
    dst[0] = z; dst[256] = z;
  }
  #pragma unroll
  for (int r=0;r<2;r++){
    int idx = r*256 + tid; int t = idx >> 6, lane = idx & 63;
    ((float4*)(x_lds + t*DIN))[lane] =
        ((const float4*)(hidden + (size_t)(t0+t)*DMODEL))[lane];
  }
  #pragma unroll
  for (int r=0;r<2;r++){
    int idx = r*256 + tid; int t = idx >> 6, j = idx & 63;
    float acc = bfe[j];
    #pragma unroll
    for (int f=0; f<NFEAT; f++) acc += feat[(size_t)(t0+t)*NFEAT + f] * Wf[f*DFEAT + j];
    x_lds[t*DIN + DMODEL + j] = acc;
  }
  __syncthreads();

  // hr = gelu(x @ Wr1 + br1): thread = (jq -> 4 cols, tg -> 2 tokens)
  const int jq = tid & 63;
  const int tg = tid >> 6;
  {
    float4 b4 = ((const float4*)br1)[jq];
    float4 acc0 = b4, acc1 = b4;
    const float4* W1 = ((const float4*)Wr1) + jq;   // row stride 64 float4

    auto fma4 = [&](int i4, const float4 (&w)[4]){
      float4 xa = *(const float4*)&x_lds[(tg*2+0)*DIN + i4*4];
      float4 xb = *(const float4*)&x_lds[(tg*2+1)*DIN + i4*4];
      acc0.x += xa.x*w[0].x + xa.y*w[1].x + xa.z*w[2].x + xa.w*w[3].x;
      acc0.y += xa.x*w[0].y + xa.y*w[1].y + xa.z*w[2].y + xa.w*w[3].y;
      acc0.z += xa.x*w[0].z + xa.y*w[1].z + xa.z*w[2].z + xa.w*w[3].z;
      acc0.w += xa.x*w[0].w + xa.y*w[1].w + xa.z*w[2].w + xa.w*w[3].w;
      acc1.x += xb.x*w[0].x + xb.y*w[1].x + xb.z*w[2].x + xb.w*w[3].x;
      acc1.y += xb.x*w[0].y + xb.y*w[1].y + xb.z*w[2].y + xb.w*w[3].y;
      acc1.z += xb.x*w[0].z + xb.y*w[1].z + xb.z*w[2].z + xb.w*w[3].z;
      acc1.w += xb.x*w[0].w + xb.y*w[1].w + xb.z*w[2].w + xb.w*w[3].w;
    };
    auto ld = [&](float4 (&b)[4], int c){
      #pragma unroll
      for (int r=0;r<4;r++) b[r] = W1[(c*4+r)*64];
    };
    float4 b0[4], b1[4], b2[4], b3[4];     // 4-deep pipeline, static names
    ld(b0,0); ld(b1,1); ld(b2,2); ld(b3,3);
    for (int c=0; c<80; c+=4){
      fma4(c+0,b0); if (c+4<80) ld(b0,c+4);
      fma4(c+1,b1); if (c+5<80) ld(b1,c+5);
      fma4(c+2,b2); if (c+6<80) ld(b2,c+6);
      fma4(c+3,b3); if (c+7<80) ld(b3,c+7);
    }
    *(float4*)&hr_lds[(tg*2+0)*260 + jq*4] =
        make_float4(gelu_tanh(acc0.x),gelu_tanh(acc0.y),gelu_tanh(acc0.z),gelu_tanh(acc0.w));
    *(float4*)&hr_lds[(tg*2+1)*260 + jq*4] =
        make_float4(gelu_tanh(acc1.x),gelu_tanh(acc1.y),gelu_tanh(acc1.z),gelu_tanh(acc1.w));
  }
  __syncthreads();
  // gate logits, 4-way split dot
  {
    int q = tid >> 6, rr = tid & 63, t = rr >> 3, e = rr & 7;
    float a0=0.f, a1=0.f, a2=0.f, a3=0.f;
    #pragma unroll 4
    for (int k4=0;k4<16;k4++){
      float4 h4 = ((const float4*)hr_lds)[t*65 + q*16 + k4];
      int row = q*64 + k4*4;
      a0 += h4.x * Wr2[(row+0)*NE + e];
      a1 += h4.y * Wr2[(row+1)*NE + e];
      a2 += h4.z * Wr2[(row+2)*NE + e];
      a3 += h4.w * Wr2[(row+3)*NE + e];
    }
    part_lds[tid] = (a0+a1)+(a2+a3);
  }
  __syncthreads();
  if (tid < TB*NE){
    int t = tid >> 3, e = tid & 7;
    float lg = br2[e] + part_lds[tid] + part_lds[tid+64] + part_lds[tid+128] + part_lds[tid+192];
    out[OUT_LOGITS + (size_t)(t0+t)*NE + e] = lg;   // TEMP == 1.0
    lg_lds[t*NE + e] = lg;
  }
  __syncthreads();
  if (tid < TB){
    int t = tid;
    float v1 = lg_lds[t*NE]; int i1 = 0;
    #pragma unroll
    for (int e=1;e<NE;e++){ float v = lg_lds[t*NE+e]; if (v > v1){ v1 = v; i1 = e; } }
    float v2 = -3.4e38f; int i2 = -1;
    #pragma unroll
    for (int e=0;e<NE;e++){
      if (e == i1) continue;
      float v = lg_lds[t*NE+e]; if (v > v2){ v2 = v; i2 = e; }
    }
    float d   = expf(v2 - v1);
    float inv = 1.0f/(1.0f + d);
    float w1 = inv, w2 = d*inv;
    #pragma unroll
    for (int e=0;e<NE;e++){
      float gv = (e==i1) ? w1 : ((e==i2) ? w2 : 0.f);
      out[OUT_GATEW + (size_t)(t0+t)*NE + e] = gv;
    }
    int p1 = atomicAdd(&cnts[i1], 1);
    lists[i1*N_TOK + p1] = (unsigned)(((t0+t)<<1));
    int p2 = atomicAdd(&cnts[i2], 1);
    lists[i2*N_TOK + p2] = (unsigned)(((t0+t)<<1) | 1);
    topw[(t0+t)*2]   = w1;
    topw[(t0+t)*2+1] = w2;
  }
}

// ---- expert: split-bf16 MFMA, batched double-buffered B prefetch ----
#define XLOFF 10496
#define HELOFF 16640
__global__ __launch_bounds__(256) void k_expert(
    const float* __restrict__ hidden, const float* __restrict__ feat,
    const float* __restrict__ Wf, const float* __restrict__ bfe,
    const int* __restrict__ cnts, const unsigned* __restrict__ lists,
    const float* __restrict__ topw,
    const unsigned short* __restrict__ W1h, const unsigned short* __restrict__ W1l,
    const unsigned short* __restrict__ W2h, const unsigned short* __restrict__ W2l,
    const float* __restrict__ be1, const float* __restrict__ be2,
    float* __restrict__ out)
{
  __shared__ unsigned short sm[33280];   // 66560 B union: x planes -> he planes
  __shared__ int   tok_lds[TE];
  __shared__ float w_lds[TE];

  const int e    = blockIdx.x & 7;      // expert pins to XCD e (weights L2-hot)
  const int tile = blockIdx.x >> 3;
  const int cnt  = cnts[e];
  const int start = tile * TE;
  if (start >= cnt) return;
  const int ntk = min(TE, cnt - start);
  const int tid = threadIdx.x;

  if (tid < TE){
    if (tid < ntk){
      unsigned ent = lists[e*N_TOK + start + tid];
      int tok = (int)(ent >> 1);
      tok_lds[tid] = tok;
      w_lds[tid]   = topw[tok*2 + (ent & 1)];
    } else { tok_lds[tid] = -1; w_lds[tid] = 0.f; }
  }
  __syncthreads();
  // stage x split-bf16
  {
    int lane = tid & 63, tq = tid >> 6;
    #pragma unroll
    for (int r=0;r<8;r++){
      int t = r*4 + tq;
      int tok = tok_lds[t];
      float4 h4 = make_float4(0.f,0.f,0.f,0.f);
      if (tok >= 0) h4 = ((const float4*)(hidden + (size_t)tok*DMODEL))[lane];
      unsigned short h0=f2bf(h4.x),h1=f2bf(h4.y),h2=f2bf(h4.z),h3=f2bf(h4.w);
      unsigned short l0=f2bf(h4.x-bf2f(h0)),l1=f2bf(h4.y-bf2f(h1)),
                     l2=f2bf(h4.z-bf2f(h2)),l3=f2bf(h4.w-bf2f(h3));
      uint2 hp, lp;
      hp.x = (unsigned)h0 | ((unsigned)h1<<16); hp.y = (unsigned)h2 | ((unsigned)h3<<16);
      lp.x = (unsigned)l0 | ((unsigned)l1<<16); lp.y = (unsigned)l2 | ((unsigned)l3<<16);
      *(uint2*)&sm[t*328 + lane*4]         = hp;
      *(uint2*)&sm[XLOFF + t*328 + lane*4] = lp;
    }
  }
  #pragma unroll
  for (int r=0;r<8;r++){
    int idx = r*256 + tid; int t = idx >> 6, j = idx & 63;
    int tok = tok_lds[t];
    float acc = 0.f;
    if (tok >= 0){
      acc = bfe[j];
      #pragma unroll
      for (int f=0; f<NFEAT; f++) acc += feat[(size_t)tok*NFEAT + f] * Wf[f*DFEAT + j];
    }
    unsigned short h = f2bf(acc);
    sm[t*328 + DMODEL + j]         = h;
    sm[XLOFF + t*328 + DMODEL + j] = f2bf(acc - bf2f(h));
  }
  __syncthreads();

  const int wv = tid >> 6;      // wave 0..3
  const int l  = tid & 63;
  const int lg = l >> 4;
  const int lr = l & 15;

  // mm6: split-bf16 triple product on two m-tiles (same acc-update order as R4)
  auto mm6 = [&](v4f &c0, v4f &c1, v8s ah0, v8s ah1, v8s al0, v8s al1, v8s bh, v8s bl){
    c0 = __builtin_amdgcn_mfma_f32_16x16x32_bf16(ah0, bh, c0, 0,0,0);
    c1 = __builtin_amdgcn_mfma_f32_16x16x32_bf16(ah1, bh, c1, 0,0,0);
    c0 = __builtin_amdgcn_mfma_f32_16x16x32_bf16(al0, bh, c0, 0,0,0);
    c1 = __builtin_amdgcn_mfma_f32_16x16x32_bf16(al1, bh, c1, 0,0,0);
    c0 = __builtin_amdgcn_mfma_f32_16x16x32_bf16(ah0, bl, c0, 0,0,0);
    c1 = __builtin_amdgcn_mfma_f32_16x16x32_bf16(ah1, bl, c1, 0,0,0);
  };

  // phase 1: he = gelu(x @ We1[e] + be1); wave owns 8 n-tiles; half-ks batches
  v4f acc1[2][8];
  {
    v4f z = {0.f,0.f,0.f,0.f};
    #pragma unroll
    for (int m=0;m<2;m++)
      #pragma unroll
      for (int j=0;j<8;j++) acc1[m][j] = z;
    const unsigned short* p1h = W1h + (size_t)e*163840;
    const unsigned short* p1l = W1l + (size_t)e*163840;
    auto ldB1 = [&](int ks, int jh, v8s (&bh)[4], v8s (&bl)[4]){
      #pragma unroll
      for (int j=0;j<4;++j){
        size_t boff = ((size_t)(ks*32 + wv*8 + jh*4 + j)*64 + l)*8;
        bh[j] = *(const v8s*)(p1h + boff);
        bl[j] = *(const v8s*)(p1l + boff);
      }
    };
    v8s bh_a[4], bl_a[4], bh_b[4], bl_b[4];   // static double buffer
    ldB1(0,0,bh_a,bl_a);
    for (int ks=0; ks<10; ++ks){
      v8s ah0 = *(const v8s*)&sm[( 0+lr)*328 + ks*32 + lg*8];
      v8s ah1 = *(const v8s*)&sm[(16+lr)*328 + ks*32 + lg*8];
      v8s al0 = *(const v8s*)&sm[XLOFF + ( 0+lr)*328 + ks*32 + lg*8];
      v8s al1 = *(const v8s*)&sm[XLOFF + (16+lr)*328 + ks*32 + lg*8];
      ldB1(ks,1,bh_b,bl_b);                       // prefetch half-batch B
      #pragma unroll
      for (int j=0;j<4;++j) mm6(acc1[0][j], acc1[1][j], ah0,ah1,al0,al1, bh_a[j], bl_a[j]);
      if (ks<9) ldB1(ks+1,0,bh_a,bl_a);           // prefetch next ks half-A
      #pragma unroll
      for (int j=0;j<4;++j) mm6(acc1[0][4+j], acc1[1][4+j], ah0,ah1,al0,al1, bh_b[j], bl_b[j]);
    }
  }
  __syncthreads();   // x dead -> he planes
  {
    #pragma unroll
    for (int j=0;j<8;++j){
      int col = (wv*8+j)*16 + lr;
      float b1 = be1[e*DH + col];
      #pragma unroll
      for (int m=0;m<2;m++)
        #pragma unroll
        for (int r=0;r<4;r++){
          float v = gelu_tanh(acc1[m][j][r] + b1);
          int row = m*16 + lg*4 + r;
          unsigned short h = f2bf(v);
          sm[row*520 + col]          = h;
          sm[HELOFF + row*520 + col] = f2bf(v - bf2f(h));
        }
    }
  }
  __syncthreads();
  // phase 2: eo = he @ We2[e] + be2; wave owns 4 n-tiles; ks-batches, unroll-2
  v4f acc2[2][4];
  {
    v4f z = {0.f,0.f,0.f,0.f};
    #pragma unroll
    for (int m=0;m<2;m++)
      #pragma unroll
      for (int j=0;j<4;j++) acc2[m][j] = z;
    const unsigned short* p2h = W2h + (size_t)e*131072;
    const unsigned short* p2l = W2l + (size_t)e*131072;
    auto ldB2 = [&](int ks, v8s (&bh)[4], v8s (&bl)[4]){
      #pragma unroll
      for (int j=0;j<4;++j){
        size_t boff = ((size_t)(ks*16 + wv*4 + j)*64 + l)*8;
        bh[j] = *(const v8s*)(p2h + boff);
        bl[j] = *(const v8s*)(p2l + boff);
      }
    };
    v8s bh_a[4], bl_a[4], bh_b[4], bl_b[4];
    ldB2(0,bh_a,bl_a);
    for (int ks=0; ks<16; ks+=2){
      v8s ah0 = *(const v8s*)&sm[( 0+lr)*520 + ks*32 + lg*8];
      v8s ah1 = *(const v8s*)&sm[(16+lr)*520 + ks*32 + lg*8];
      v8s al0 = *(const v8s*)&sm[HELOFF + ( 0+lr)*520 + ks*32 + lg*8];
      v8s al1 = *(const v8s*)&sm[HELOFF + (16+lr)*520 + ks*32 + lg*8];
      ldB2(ks+1, bh_b, bl_b);
      #pragma unroll
      for (int j=0;j<4;++j) mm6(acc2[0][j], acc2[1][j], ah0,ah1,al0,al1, bh_a[j], bl_a[j]);
      v8s ch0 = *(const v8s*)&sm[( 0+lr)*520 + (ks+1)*32 + lg*8];
      v8s ch1 = *(const v8s*)&sm[(16+lr)*520 + (ks+1)*32 + lg*8];
      v8s cl0 = *(const v8s*)&sm[HELOFF + ( 0+lr)*520 + (ks+1)*32 + lg*8];
      v8s cl1 = *(const v8s*)&sm[HELOFF + (16+lr)*520 + (ks+1)*32 + lg*8];
      if (ks+2<16) ldB2(ks+2, bh_a, bl_a);
      #pragma unroll
      for (int j=0;j<4;++j) mm6(acc2[0][j], acc2[1][j], ch0,ch1,cl0,cl1, bh_b[j], bl_b[j]);
    }
  }
  // epilogue 2: + be2, * gate, atomicAdd into stage_delta
  {
    #pragma unroll
    for (int j=0;j<4;++j){
      int col = (wv*4+j)*16 + lr;
      float b2 = be2[e*DMODEL + col];
      #pragma unroll
      for (int m=0;m<2;m++)
        #pragma unroll
        for (int r=0;r<4;r++){
          int row = m*16 + lg*4 + r;
          if (row < ntk){
            float w = w_lds[row];
            atomicAdd(out + (size_t)tok_lds[row]*DMODEL + col,
                      w*(acc2[m][j][r] + b2));
          }
        }
    }
  }
}

extern "C" void kernel_launch(void* const* d_in, const int* in_sizes, int n_in,
                              void* d_out, int out_size, void* d_ws, size_t ws_size,
                              hipStream_t stream)
{
  (void)in_sizes; (void)n_in; (void)out_size; (void)ws_size;
  const float* hidden = (const float*)d_in[0];
  const float* feat   = (const float*)d_in[1];
  const float* Wf     = (const float*)d_in[2];
  const float* bfe    = (const float*)d_in[3];
  const float* Wr1    = (const float*)d_in[4];
  const float* br1    = (const float*)d_in[5];
  const float* Wr2    = (const float*)d_in[6];
  const float* br2    = (const float*)d_in[7];
  const float* We1    = (const float*)d_in[8];
  const float* be1    = (const float*)d_in[9];
  const float* We2    = (const float*)d_in[10];
  const float* be2    = (const float*)d_in[11];
  float* out = (float*)d_out;

  // ws layout (bytes): cnts@0, lists@256, topw@262400,
  //   W1h@327936, W1l@2949376, W2h@5570816, W2l@7667968  (~9.77 MB)
  char* ws = (char*)d_ws;
  int*      cnts  = (int*)ws;
  unsigned* lists = (unsigned*)(ws + 256);
  float*    topw  = (float*)(ws + 262400);
  unsigned short* W1h = (unsigned short*)(ws + 327936);
  unsigned short* W1l = (unsigned short*)(ws + 2949376);
  unsigned short* W2h = (unsigned short*)(ws + 5570816);
  unsigned short* W2l = (unsigned short*)(ws + 7667968);

  hipLaunchKernelGGL(k_init, dim3(1), dim3(64), 0, stream, cnts);
  hipLaunchKernelGGL(k_prep1, dim3(640), dim3(256), 0, stream, We1, W1h, W1l);
  hipLaunchKernelGGL(k_prep2, dim3(512), dim3(256), 0, stream, We2, W2h, W2l);
  hipLaunchKernelGGL(k_router, dim3(N_TOK/TB), dim3(256), 0, stream,
                     hidden, feat, Wf, bfe, Wr1, br1, Wr2, br2,
                     out, cnts, lists, topw);
  hipLaunchKernelGGL(k_expert, dim3((N_TOK/TE)*NE), dim3(256), 0, stream,
                     hidden, feat, Wf, bfe, cnts, lists, topw,
                     W1h, W1l, W2h, W2l, be1, be2, out);
}

// Round 7
// 293.827 us; speedup vs baseline: 1.9269x; 1.0665x over previous
//
#include <hip/hip_runtime.h>
#include <hip/hip_bf16.h>

// Problem: B=32, L=256 -> 8192 tokens; DIN=320, DR=256, DH=512, E=8, top-2.
#define N_TOK   8192
#define DMODEL  256
#define NFEAT   8
#define DFEAT   64
#define DIN     320
#define DRTR    256
#define NE      8
#define DH      512
#define TE      32      // tokens per expert tile
#define RTB     32      // tokens per router block
#define FIXCAP  128
#define FIXTHR  2e-3f

// d_out layout (floats): [stage_delta 8192*256][gate_weights 8192*8][gate_logits 8192*8]
#define OUT_GATEW  (N_TOK*DMODEL)
#define OUT_LOGITS (N_TOK*DMODEL + N_TOK*NE)

typedef short v8s __attribute__((ext_vector_type(8)));   // 8 bf16 (4 VGPR) MFMA A/B frag
typedef float v4f __attribute__((ext_vector_type(4)));   // 4 f32 MFMA C/D frag

__device__ __forceinline__ unsigned short f2bf(float f){   // RNE f32->bf16
  unsigned u = __float_as_uint(f);
  return (unsigned short)((u + 0x7FFFu + ((u>>16)&1u)) >> 16);
}
__device__ __forceinline__ float bf2f(unsigned short h){
  return __uint_as_float(((unsigned)h)<<16);
}
__device__ __forceinline__ float gelu_tanh(float v){
  float u = 0.7978845608028654f * (v + 0.044715f * v * v * v);
  float a = fabsf(u);
  float e = __expf(-2.0f * a);
  float t = (1.0f - e) / (1.0f + e);
  t = copysignf(t, u);
  return 0.5f * v * (1.0f + t);
}

__global__ void k_init(int* __restrict__ cnts, int* __restrict__ nfix){
  if (threadIdx.x < NE) cnts[threadIdx.x] = 0;
  if (threadIdx.x == NE) *nfix = 0;
}

// ---- weight preps: split-bf16 (hi+lo) planes in MFMA B-fragment order ----
// plane[((kstep*NT + nt))*64 + lane]*8+i -> W[k=kstep*32+(lane>>4)*8+i][n=nt*16+(lane&15)]
__global__ __launch_bounds__(256) void k_prep1(const float* __restrict__ W,
                                               unsigned short* __restrict__ dh,
                                               unsigned short* __restrict__ dl){
  int gid = blockIdx.x*256 + threadIdx.x;        // 8*10*32*64
  int l = gid & 63; int w = gid >> 6;
  int nt = w & 31; w >>= 5; int kstep = w % 10; int e = w / 10;
  int n = nt*16 + (l&15);
  int kb = kstep*32 + ((l>>4)<<3);
  const float* src = W + ((size_t)e*DIN + kb)*DH + n;
  unsigned short hs[8], ls[8];
  #pragma unroll
  for (int i=0;i<8;i++){
    float v = src[(size_t)i*DH];
    unsigned short h = f2bf(v);
    hs[i] = h; ls[i] = f2bf(v - bf2f(h));
  }
  size_t off = (size_t)gid*8;
  *(v8s*)(dh+off) = *(v8s*)hs;
  *(v8s*)(dl+off) = *(v8s*)ls;
}

__global__ __launch_bounds__(256) void k_prep2(const float* __restrict__ W,
                                               unsigned short* __restrict__ dh,
                                               unsigned short* __restrict__ dl){
  int gid = blockIdx.x*256 + threadIdx.x;        // 8*16*16*64
  int l = gid & 63; int w = gid >> 6;
  int nt = w & 15; w >>= 4; int kstep = w & 15; int e = w >> 4;
  int n = nt*16 + (l&15);
  int kb = kstep*32 + ((l>>4)<<3);
  const float* src = W + ((size_t)e*DH + kb)*DMODEL + n;
  unsigned short hs[8], ls[8];
  #pragma unroll
  for (int i=0;i<8;i++){
    float v = src[(size_t)i*DMODEL];
    unsigned short h = f2bf(v);
    hs[i] = h; ls[i] = f2bf(v - bf2f(h));
  }
  size_t off = (size_t)gid*8;
  *(v8s*)(dh+off) = *(v8s*)hs;
  *(v8s*)(dl+off) = *(v8s*)ls;
}

__global__ __launch_bounds__(256) void k_prepr(const float* __restrict__ W,
                                               unsigned short* __restrict__ dh,
                                               unsigned short* __restrict__ dl){
  int gid = blockIdx.x*256 + threadIdx.x;        // 10*16*64 = 10240
  if (gid >= 10240) return;
  int l = gid & 63; int w = gid >> 6;
  int nt = w & 15; int kstep = w >> 4;           // 0..9
  int n = nt*16 + (l&15);
  int kb = kstep*32 + ((l>>4)<<3);
  const float* src = W + (size_t)kb*DRTR + n;
  unsigned short hs[8], ls[8];
  #pragma unroll
  for (int i=0;i<8;i++){
    float v = src[(size_t)i*DRTR];
    unsigned short h = f2bf(v);
    hs[i] = h; ls[i] = f2bf(v - bf2f(h));
  }
  size_t off = (size_t)gid*8;
  *(v8s*)(dh+off) = *(v8s*)hs;
  *(v8s*)(dl+off) = *(v8s*)ls;
}

// mm6: split-bf16 triple product on two m-tiles
#define MM6(c0,c1,ah0,ah1,al0,al1,bh,bl) do{ \
  c0 = __builtin_amdgcn_mfma_f32_16x16x32_bf16(ah0, bh, c0, 0,0,0); \
  c1 = __builtin_amdgcn_mfma_f32_16x16x32_bf16(ah1, bh, c1, 0,0,0); \
  c0 = __builtin_amdgcn_mfma_f32_16x16x32_bf16(al0, bh, c0, 0,0,0); \
  c1 = __builtin_amdgcn_mfma_f32_16x16x32_bf16(al1, bh, c1, 0,0,0); \
  c0 = __builtin_amdgcn_mfma_f32_16x16x32_bf16(ah0, bl, c0, 0,0,0); \
  c1 = __builtin_amdgcn_mfma_f32_16x16x32_bf16(ah1, bl, c1, 0,0,0); }while(0)

#define XLOFF  10496   // ushort offset of xl plane ([32][328])
#define HELOFF 16640   // ushort offset of hel plane ([32][520])

// ---- router: split-bf16 MFMA hr + fp32 logits; near-tie tokens deferred ----
// 256 blocks x 512 thr (8 waves). LDS: x planes 42KB (hr fp32 [32][264] overlays).
__global__ __launch_bounds__(512) void k_rmfma(
    const float* __restrict__ hidden, const float* __restrict__ feat,
    const float* __restrict__ Wf, const float* __restrict__ bfe,
    const unsigned short* __restrict__ Wr1h, const unsigned short* __restrict__ Wr1l,
    const float* __restrict__ br1,
    const float* __restrict__ Wr2, const float* __restrict__ br2,
    float* __restrict__ out,
    int* __restrict__ cnts, unsigned* __restrict__ lists, float* __restrict__ topw,
    int* __restrict__ nfix, int* __restrict__ fixlist)
{
  __shared__ unsigned short sm[21248];   // 42496 B: xh@0 [32][328], xl@XLOFF; later hr f32 [32][264]
  __shared__ float part_lds[512];
  __shared__ float lg_lds[RTB*NE];
  float* hrf = (float*)sm;
  const int tid = threadIdx.x;
  const int t0 = blockIdx.x * RTB;

  // zero this block's stage_delta slab (32*256 floats = 2048 f4)
  {
    float4 z = make_float4(0.f,0.f,0.f,0.f);
    float4* dst = ((float4*)out) + (size_t)blockIdx.x*2048 + tid;
    #pragma unroll
    for (int r=0;r<4;r++) dst[r*512] = z;
  }
  // stage x split-bf16: hidden rows
  #pragma unroll
  for (int r=0;r<4;r++){
    int idx = r*512 + tid; int t = idx >> 6, lane = idx & 63;
    float4 h4 = ((const float4*)(hidden + (size_t)(t0+t)*DMODEL))[lane];
    unsigned short h0=f2bf(h4.x),h1=f2bf(h4.y),h2=f2bf(h4.z),h3=f2bf(h4.w);
    unsigned short l0=f2bf(h4.x-bf2f(h0)),l1=f2bf(h4.y-bf2f(h1)),
                   l2=f2bf(h4.z-bf2f(h2)),l3=f2bf(h4.w-bf2f(h3));
    uint2 hp, lp;
    hp.x=(unsigned)h0|((unsigned)h1<<16); hp.y=(unsigned)h2|((unsigned)h3<<16);
    lp.x=(unsigned)l0|((unsigned)l1<<16); lp.y=(unsigned)l2|((unsigned)l3<<16);
    *(uint2*)&sm[t*328 + lane*4]         = hp;
    *(uint2*)&sm[XLOFF + t*328 + lane*4] = lp;
  }
  // feature embedding
  #pragma unroll
  for (int r=0;r<4;r++){
    int idx = r*512 + tid; int t = idx >> 6, j = idx & 63;
    float acc = bfe[j];
    #pragma unroll
    for (int f=0; f<NFEAT; f++) acc += feat[(size_t)(t0+t)*NFEAT + f] * Wf[f*DFEAT + j];
    unsigned short h = f2bf(acc);
    sm[t*328 + DMODEL + j]         = h;
    sm[XLOFF + t*328 + DMODEL + j] = f2bf(acc - bf2f(h));
  }
  __syncthreads();

  const int wv = tid >> 6;      // 0..7
  const int l  = tid & 63;
  const int lg = l >> 4;
  const int lr = l & 15;

  // hr = x @ Wr1 (split-bf16): wave owns 2 n-tiles, ks 0..9, double-buffered B
  v4f acc[2][2];
  {
    v4f z = {0.f,0.f,0.f,0.f};
    acc[0][0]=z; acc[0][1]=z; acc[1][0]=z; acc[1][1]=z;
    v8s bh_a[2], bl_a[2], bh_b[2], bl_b[2];
    auto ldBr = [&](int ks, v8s (&bh)[2], v8s (&bl)[2]){
      #pragma unroll
      for (int j=0;j<2;++j){
        size_t boff = ((size_t)(ks*16 + wv*2 + j)*64 + l)*8;
        bh[j] = *(const v8s*)(Wr1h + boff);
        bl[j] = *(const v8s*)(Wr1l + boff);
      }
    };
    ldBr(0, bh_a, bl_a);
    for (int ks=0; ks<10; ks+=2){
      v8s ah0 = *(const v8s*)&sm[( 0+lr)*328 + ks*32 + lg*8];
      v8s ah1 = *(const v8s*)&sm[(16+lr)*328 + ks*32 + lg*8];
      v8s al0 = *(const v8s*)&sm[XLOFF + ( 0+lr)*328 + ks*32 + lg*8];
      v8s al1 = *(const v8s*)&sm[XLOFF + (16+lr)*328 + ks*32 + lg*8];
      ldBr(ks+1, bh_b, bl_b);
      #pragma unroll
      for (int j=0;j<2;++j) MM6(acc[0][j],acc[1][j], ah0,ah1,al0,al1, bh_a[j],bl_a[j]);
      v8s ch0 = *(const v8s*)&sm[( 0+lr)*328 + (ks+1)*32 + lg*8];
      v8s ch1 = *(const v8s*)&sm[(16+lr)*328 + (ks+1)*32 + lg*8];
      v8s cl0 = *(const v8s*)&sm[XLOFF + ( 0+lr)*328 + (ks+1)*32 + lg*8];
      v8s cl1 = *(const v8s*)&sm[XLOFF + (16+lr)*328 + (ks+1)*32 + lg*8];
      if (ks+2<10) ldBr(ks+2, bh_a, bl_a);
      #pragma unroll
      for (int j=0;j<2;++j) MM6(acc[0][j],acc[1][j], ch0,ch1,cl0,cl1, bh_b[j],bl_b[j]);
    }
  }
  __syncthreads();    // x planes dead -> hr fp32 overlay
  // epilogue: bias + gelu, fp32 into hrf[row][col] (stride 264)
  #pragma unroll
  for (int j=0;j<2;++j){
    int col = (wv*2+j)*16 + lr;
    float b1 = br1[col];
    #pragma unroll
    for (int m=0;m<2;m++)
      #pragma unroll
      for (int r=0;r<4;r++){
        int row = m*16 + lg*4 + r;
        hrf[row*264 + col] = gelu_tanh(acc[m][j][r] + b1);
      }
  }
  __syncthreads();
  // logits: fp32 VALU. tid = q*256 + t*8 + e (q=ksplit of 128, t token, e expert)
  {
    int q = tid >> 8, rr = tid & 255, t = rr >> 3, e = rr & 7;
    float a0=0.f,a1=0.f,a2=0.f,a3=0.f;
    #pragma unroll 4
    for (int k4=0;k4<32;k4++){
      float4 h4 = ((const float4*)hrf)[t*66 + q*32 + k4];
      int row = q*128 + k4*4;
      a0 += h4.x * Wr2[(row+0)*NE + e];
      a1 += h4.y * Wr2[(row+1)*NE + e];
      a2 += h4.z * Wr2[(row+2)*NE + e];
      a3 += h4.w * Wr2[(row+3)*NE + e];
    }
    part_lds[tid] = (a0+a1)+(a2+a3);
  }
  __syncthreads();
  if (tid < RTB*NE){
    int t = tid >> 3, e = tid & 7;
    float lgv = br2[e] + part_lds[tid] + part_lds[tid+256];
    out[OUT_LOGITS + (size_t)(t0+t)*NE + e] = lgv;   // TEMP == 1.0
    lg_lds[t*NE + e] = lgv;
  }
  __syncthreads();
  // top-3 scan; defer near-ties (v2-v3 gap) to exact fix path
  if (tid < RTB){
    int t = tid, tok = t0 + t;
    float v1=-3.4e38f, v2=-3.4e38f, v3=-3.4e38f; int i1=-1, i2=-1;
    #pragma unroll
    for (int e=0;e<NE;e++){
      float v = lg_lds[t*NE+e];
      if (v > v1){ v3=v2; v2=v1; i2=i1; v1=v; i1=e; }
      else if (v > v2){ v3=v2; v2=v; i2=e; }
      else if (v > v3){ v3=v; }
    }
    bool defer = false;
    if (v2 - v3 < FIXTHR){
      int fi = atomicAdd(nfix, 1);
      if (fi < FIXCAP){ fixlist[fi] = tok; defer = true; }
    }
    if (!defer){
      float d   = expf(v2 - v1);
      float inv = 1.0f/(1.0f + d);
      float w1 = inv, w2 = d*inv;
      #pragma unroll
      for (int e=0;e<NE;e++){
        float gv = (e==i1) ? w1 : ((e==i2) ? w2 : 0.f);
        out[OUT_GATEW + (size_t)tok*NE + e] = gv;
      }
      int p1 = atomicAdd(&cnts[i1], 1);
      lists[i1*N_TOK + p1] = (unsigned)(tok<<1);
      int p2 = atomicAdd(&cnts[i2], 1);
      lists[i2*N_TOK + p2] = (unsigned)((tok<<1) | 1);
      topw[tok*2]   = w1;
      topw[tok*2+1] = w2;
    }
  }
}

// ---- exact fp32 recompute of logits for flagged tokens (rare) ----
__global__ __launch_bounds__(256) void k_fix(
    const float* __restrict__ hidden, const float* __restrict__ feat,
    const float* __restrict__ Wf, const float* __restrict__ bfe,
    const float* __restrict__ Wr1, const float* __restrict__ br1,
    const float* __restrict__ Wr2, const float* __restrict__ br2,
    float* __restrict__ out, const int* __restrict__ nfix, const int* __restrict__ fixlist)
{
  int nf = *nfix; if (nf > FIXCAP) nf = FIXCAP;
  if ((int)blockIdx.x >= nf) return;
  const int tok = fixlist[blockIdx.x];
  const int tid = threadIdx.x;
  __shared__ float xf[DIN];
  __shared__ float hr[DRTR];
  if (tid < DMODEL) xf[tid] = hidden[(size_t)tok*DMODEL + tid];
  if (tid < DFEAT){
    float acc = bfe[tid];
    #pragma unroll
    for (int f=0; f<NFEAT; f++) acc += feat[(size_t)tok*NFEAT + f] * Wf[f*DFEAT + tid];
    xf[DMODEL + tid] = acc;
  }
  __syncthreads();
  {
    float acc = br1[tid];
    for (int i=0;i<DIN;i++) acc += xf[i] * Wr1[(size_t)i*DRTR + tid];
    hr[tid] = gelu_tanh(acc);
  }
  __syncthreads();
  if (tid < NE){
    float acc = br2[tid];
    for (int i=0;i<DRTR;i++) acc += hr[i] * Wr2[i*NE + tid];
    out[OUT_LOGITS + (size_t)tok*NE + tid] = acc;
  }
}

// ---- gate the flagged tokens from final (exact) logits ----
__global__ void k_gatefix(float* __restrict__ out,
                          int* __restrict__ cnts, unsigned* __restrict__ lists,
                          float* __restrict__ topw,
                          const int* __restrict__ nfix, const int* __restrict__ fixlist)
{
  int nf = *nfix; if (nf > FIXCAP) nf = FIXCAP;
  int i = threadIdx.x;
  if (i >= nf) return;
  int tok = fixlist[i];
  float v1=-3.4e38f, v2=-3.4e38f; int i1=-1, i2=-1;
  #pragma unroll
  for (int e=0;e<NE;e++){
    float v = out[OUT_LOGITS + (size_t)tok*NE + e];
    if (v > v1){ v2=v1; i2=i1; v1=v; i1=e; }
    else if (v > v2){ v2=v; i2=e; }
  }
  float d   = expf(v2 - v1);
  float inv = 1.0f/(1.0f + d);
  float w1 = inv, w2 = d*inv;
  #pragma unroll
  for (int e=0;e<NE;e++){
    float gv = (e==i1) ? w1 : ((e==i2) ? w2 : 0.f);
    out[OUT_GATEW + (size_t)tok*NE + e] = gv;
  }
  int p1 = atomicAdd(&cnts[i1], 1);
  lists[i1*N_TOK + p1] = (unsigned)(tok<<1);
  int p2 = atomicAdd(&cnts[i2], 1);
  lists[i2*N_TOK + p2] = (unsigned)((tok<<1) | 1);
  topw[tok*2]   = w1;
  topw[tok*2+1] = w2;
}

// ---- expert: split-bf16 MFMA, 8 waves (4 waves/SIMD), db B prefetch ----
__global__ __launch_bounds__(512) void k_expert(
    const float* __restrict__ hidden, const float* __restrict__ feat,
    const float* __restrict__ Wf, const float* __restrict__ bfe,
    const int* __restrict__ cnts, const unsigned* __restrict__ lists,
    const float* __restrict__ topw,
    const unsigned short* __restrict__ W1h, const unsigned short* __restrict__ W1l,
    const unsigned short* __restrict__ W2h, const unsigned short* __restrict__ W2l,
    const float* __restrict__ be1, const float* __restrict__ be2,
    float* __restrict__ out)
{
  __shared__ unsigned short sm[33280];   // 66560 B union: x planes -> he planes
  __shared__ int   tok_lds[TE];
  __shared__ float w_lds[TE];

  const int e    = blockIdx.x & 7;      // expert pins to XCD e (weights L2-hot)
  const int tile = blockIdx.x >> 3;
  const int cnt  = cnts[e];
  const int start = tile * TE;
  if (start >= cnt) return;
  const int ntk = min(TE, cnt - start);
  const int tid = threadIdx.x;

  if (tid < TE){
    if (tid < ntk){
      unsigned ent = lists[e*N_TOK + start + tid];
      int tok = (int)(ent >> 1);
      tok_lds[tid] = tok;
      w_lds[tid]   = topw[tok*2 + (ent & 1)];
    } else { tok_lds[tid] = -1; w_lds[tid] = 0.f; }
  }
  __syncthreads();
  // stage x split-bf16
  #pragma unroll
  for (int r=0;r<4;r++){
    int idx = r*512 + tid; int t = idx >> 6, lane = idx & 63;
    int tok = tok_lds[t];
    float4 h4 = make_float4(0.f,0.f,0.f,0.f);
    if (tok >= 0) h4 = ((const float4*)(hidden + (size_t)tok*DMODEL))[lane];
    unsigned short h0=f2bf(h4.x),h1=f2bf(h4.y),h2=f2bf(h4.z),h3=f2bf(h4.w);
    unsigned short l0=f2bf(h4.x-bf2f(h0)),l1=f2bf(h4.y-bf2f(h1)),
                   l2=f2bf(h4.z-bf2f(h2)),l3=f2bf(h4.w-bf2f(h3));
    uint2 hp, lp;
    hp.x=(unsigned)h0|((unsigned)h1<<16); hp.y=(unsigned)h2|((unsigned)h3<<16);
    lp.x=(unsigned)l0|((unsigned)l1<<16); lp.y=(unsigned)l2|((unsigned)l3<<16);
    *(uint2*)&sm[t*328 + lane*4]         = hp;
    *(uint2*)&sm[XLOFF + t*328 + lane*4] = lp;
  }
  #pragma unroll
  for (int r=0;r<4;r++){
    int idx = r*512 + tid; int t = idx >> 6, j = idx & 63;
    int tok = tok_lds[t];
    float acc = 0.f;
    if (tok >= 0){
      acc = bfe[j];
      #pragma unroll
      for (int f=0; f<NFEAT; f++) acc += feat[(size_t)tok*NFEAT + f] * Wf[f*DFEAT + j];
    }
    unsigned short h = f2bf(acc);
    sm[t*328 + DMODEL + j]         = h;
    sm[XLOFF + t*328 + DMODEL + j] = f2bf(acc - bf2f(h));
  }
  __syncthreads();

  const int wv = tid >> 6;      // wave 0..7
  const int l  = tid & 63;
  const int lg = l >> 4;
  const int lr = l & 15;

  // phase 1: he = gelu(x @ We1[e] + be1); wave owns 4 n-tiles (2+2 halves)
  v4f acc1[2][4];
  {
    v4f z = {0.f,0.f,0.f,0.f};
    #pragma unroll
    for (int m=0;m<2;m++)
      #pragma unroll
      for (int j=0;j<4;j++) acc1[m][j] = z;
    const unsigned short* p1h = W1h + (size_t)e*163840;
    const unsigned short* p1l = W1l + (size_t)e*163840;
    auto ldB1 = [&](int ks, int jh, v8s (&bh)[2], v8s (&bl)[2]){
      #pragma unroll
      for (int j=0;j<2;++j){
        size_t boff = ((size_t)(ks*32 + wv*4 + jh*2 + j)*64 + l)*8;
        bh[j] = *(const v8s*)(p1h + boff);
        bl[j] = *(const v8s*)(p1l + boff);
      }
    };
    v8s bh_a[2], bl_a[2], bh_b[2], bl_b[2];
    ldB1(0,0,bh_a,bl_a);
    for (int ks=0; ks<10; ++ks){
      v8s ah0 = *(const v8s*)&sm[( 0+lr)*328 + ks*32 + lg*8];
      v8s ah1 = *(const v8s*)&sm[(16+lr)*328 + ks*32 + lg*8];
      v8s al0 = *(const v8s*)&sm[XLOFF + ( 0+lr)*328 + ks*32 + lg*8];
      v8s al1 = *(const v8s*)&sm[XLOFF + (16+lr)*328 + ks*32 + lg*8];
      ldB1(ks,1,bh_b,bl_b);
      #pragma unroll
      for (int j=0;j<2;++j) MM6(acc1[0][j],acc1[1][j], ah0,ah1,al0,al1, bh_a[j],bl_a[j]);
      if (ks<9) ldB1(ks+1,0,bh_a,bl_a);
      #pragma unroll
      for (int j=0;j<2;++j) MM6(acc1[0][2+j],acc1[1][2+j], ah0,ah1,al0,al1, bh_b[j],bl_b[j]);
    }
  }
  __syncthreads();   // x dead -> he planes
  #pragma unroll
  for (int j=0;j<4;++j){
    int col = (wv*4+j)*16 + lr;
    float b1 = be1[e*DH + col];
    #pragma unroll
    for (int m=0;m<2;m++)
      #pragma unroll
      for (int r=0;r<4;r++){
        float v = gelu_tanh(acc1[m][j][r] + b1);
        int row = m*16 + lg*4 + r;
        unsigned short h = f2bf(v);
        sm[row*520 + col]          = h;
        sm[HELOFF + row*520 + col] = f2bf(v - bf2f(h));
      }
  }
  __syncthreads();
  // phase 2: eo = he @ We2[e] + be2; wave owns 2 n-tiles; ks double-buffer
  v4f acc2[2][2];
  {
    v4f z = {0.f,0.f,0.f,0.f};
    acc2[0][0]=z; acc2[0][1]=z; acc2[1][0]=z; acc2[1][1]=z;
    const unsigned short* p2h = W2h + (size_t)e*131072;
    const unsigned short* p2l = W2l + (size_t)e*131072;
    auto ldB2 = [&](int ks, v8s (&bh)[2], v8s (&bl)[2]){
      #pragma unroll
      for (int j=0;j<2;++j){
        size_t boff = ((size_t)(ks*16 + wv*2 + j)*64 + l)*8;
        bh[j] = *(const v8s*)(p2h + boff);
        bl[j] = *(const v8s*)(p2l + boff);
      }
    };
    v8s bh_a[2], bl_a[2], bh_b[2], bl_b[2];
    ldB2(0,bh_a,bl_a);
    for (int ks=0; ks<16; ks+=2){
      v8s ah0 = *(const v8s*)&sm[( 0+lr)*520 + ks*32 + lg*8];
      v8s ah1 = *(const v8s*)&sm[(16+lr)*520 + ks*32 + lg*8];
      v8s al0 = *(const v8s*)&sm[HELOFF + ( 0+lr)*520 + ks*32 + lg*8];
      v8s al1 = *(const v8s*)&sm[HELOFF + (16+lr)*520 + ks*32 + lg*8];
      ldB2(ks+1, bh_b, bl_b);
      #pragma unroll
      for (int j=0;j<2;++j) MM6(acc2[0][j],acc2[1][j], ah0,ah1,al0,al1, bh_a[j],bl_a[j]);
      v8s ch0 = *(const v8s*)&sm[( 0+lr)*520 + (ks+1)*32 + lg*8];
      v8s ch1 = *(const v8s*)&sm[(16+lr)*520 + (ks+1)*32 + lg*8];
      v8s cl0 = *(const v8s*)&sm[HELOFF + ( 0+lr)*520 + (ks+1)*32 + lg*8];
      v8s cl1 = *(const v8s*)&sm[HELOFF + (16+lr)*520 + (ks+1)*32 + lg*8];
      if (ks+2<16) ldB2(ks+2, bh_a, bl_a);
      #pragma unroll
      for (int j=0;j<2;++j) MM6(acc2[0][j],acc2[1][j], ch0,ch1,cl0,cl1, bh_b[j],bl_b[j]);
    }
  }
  // epilogue: + be2, * gate, atomicAdd into stage_delta
  #pragma unroll
  for (int j=0;j<2;++j){
    int col = (wv*2+j)*16 + lr;
    float b2 = be2[e*DMODEL + col];
    #pragma unroll
    for (int m=0;m<2;m++)
      #pragma unroll
      for (int r=0;r<4;r++){
        int row = m*16 + lg*4 + r;
        if (row < ntk){
          float w = w_lds[row];
          atomicAdd(out + (size_t)tok_lds[row]*DMODEL + col,
                    w*(acc2[m][j][r] + b2));
        }
      }
  }
}

extern "C" void kernel_launch(void* const* d_in, const int* in_sizes, int n_in,
                              void* d_out, int out_size, void* d_ws, size_t ws_size,
                              hipStream_t stream)
{
  (void)in_sizes; (void)n_in; (void)out_size; (void)ws_size;
  const float* hidden = (const float*)d_in[0];
  const float* feat   = (const float*)d_in[1];
  const float* Wf     = (const float*)d_in[2];
  const float* bfe    = (const float*)d_in[3];
  const float* Wr1    = (const float*)d_in[4];
  const float* br1    = (const float*)d_in[5];
  const float* Wr2    = (const float*)d_in[6];
  const float* br2    = (const float*)d_in[7];
  const float* We1    = (const float*)d_in[8];
  const float* be1    = (const float*)d_in[9];
  const float* We2    = (const float*)d_in[10];
  const float* be2    = (const float*)d_in[11];
  float* out = (float*)d_out;

  // ws layout (bytes): cnts@0(8i) nfix@64 fixlist@128(128i) lists@1024 topw@263168
  //   W1h@328704 W1l@2950144 W2h@5571584 W2l@7668736 Wr1h@9765888 Wr1l@9929728 (~10.1MB)
  char* ws = (char*)d_ws;
  int*      cnts    = (int*)ws;
  int*      nfix    = (int*)(ws + 64);
  int*      fixlist = (int*)(ws + 128);
  unsigned* lists   = (unsigned*)(ws + 1024);
  float*    topw    = (float*)(ws + 263168);
  unsigned short* W1h  = (unsigned short*)(ws + 328704);
  unsigned short* W1l  = (unsigned short*)(ws + 2950144);
  unsigned short* W2h  = (unsigned short*)(ws + 5571584);
  unsigned short* W2l  = (unsigned short*)(ws + 7668736);
  unsigned short* Wr1h = (unsigned short*)(ws + 9765888);
  unsigned short* Wr1l = (unsigned short*)(ws + 9929728);

  hipLaunchKernelGGL(k_init, dim3(1), dim3(64), 0, stream, cnts, nfix);
  hipLaunchKernelGGL(k_prep1, dim3(640), dim3(256), 0, stream, We1, W1h, W1l);
  hipLaunchKernelGGL(k_prep2, dim3(512), dim3(256), 0, stream, We2, W2h, W2l);
  hipLaunchKernelGGL(k_prepr, dim3(40),  dim3(256), 0, stream, Wr1, Wr1h, Wr1l);
  hipLaunchKernelGGL(k_rmfma, dim3(N_TOK/RTB), dim3(512), 0, stream,
                     hidden, feat, Wf, bfe, Wr1h, Wr1l, br1, Wr2, br2,
                     out, cnts, lists, topw, nfix, fixlist);
  hipLaunchKernelGGL(k_fix, dim3(FIXCAP), dim3(256), 0, stream,
                     hidden, feat, Wf, bfe, Wr1, br1, Wr2, br2, out, nfix, fixlist);
  hipLaunchKernelGGL(k_gatefix, dim3(1), dim3(FIXCAP), 0, stream,
                     out, cnts, lists, topw, nfix, fixlist);
  hipLaunchKernelGGL(k_expert, dim3((N_TOK/TE)*NE), dim3(512), 0, stream,
                     hidden, feat, Wf, bfe, cnts, lists, topw,
                     W1h, W1l, W2h, W2l, be1, be2, out);
}